// Round 1
// baseline (218.890 us; speedup 1.0000x reference)
//
#include <hip/hip_runtime.h>
#include <cstdint>
#include <cstddef>

// CNLinkPredictor on MI355X — round 1: correct fp32 baseline.
//
// Pipeline:
//   1. k_bitmask : adj (0/1 fp32, 256 MB) -> bit rows [N][N/64] u64 (8 MB)
//   2. gemm      : T  = relu(x @ xlin_w1 + b1)
//   3. gemm      : H  = x + relu(T @ xlin_w2 + b2)
//   4. k_edges   : per edge e=(i,j): mask = bits[i] & bits[j];
//                  xcn[e] = sum_{k in mask} H[k];  xij_in[e] = x[i]*x[j]
//                  (avg common-neighbor count ~0.125 -> sparse gather, NOT a dense GEMM)
//   5. gemm      : XIJ  = relu(xij_in @ xij_w + xij_b)
//   6. gemm      : T2   = relu(xcn @ xcn_w1 + b1)
//   7. gemm      : XCN2 = relu(T2 @ xcn_w2 + b2)
//   8. gemm      : L1   = relu((XCN2*beta + XIJ) @ lin_w1 + lin_b1)   (z fused into A-stage)
//   9. k_gemv_out: out  = L1 @ lin_w2 + lin_b2
//
// All fp32. GEMM: 64x64 tile, 256 thr, 4x4 micro-tile, BK=16.

#define C_DIM   256
#define N_NODES 8192
#define E_EDGES 8192

// ---------------- kernel 1: adjacency -> bitmask ----------------
__global__ __launch_bounds__(256) void k_bitmask(const float* __restrict__ adj,
                                                 unsigned long long* __restrict__ bits) {
    const long long TOTAL = (long long)N_NODES * N_NODES / 64;  // 1M words
    const int  lane = threadIdx.x & 63;
    long long wid = (((long long)blockIdx.x * blockDim.x) + threadIdx.x) >> 6;
    long long nw  = ((long long)gridDim.x * blockDim.x) >> 6;
    for (long long w = wid; w < TOTAL; w += nw) {
        float v = adj[(w << 6) + lane];              // 64 lanes x 4B contiguous
        unsigned long long m = __ballot(v > 0.5f);
        if (lane == 0) bits[w] = m;
    }
}

// ---------------- GEMM: C = act(A' @ B + bias) [+resid], A' = A (*beta + A2) ----
// A:[M,256] rm, B:[256,256] rm (K rows, N cols). M multiple of 64.
template<bool FUSE_Z, bool RESID, bool RELU>
__global__ __launch_bounds__(256) void k_gemm256(
    const float* __restrict__ A, const float* __restrict__ A2,
    const float* __restrict__ betap,
    const float* __restrict__ B, const float* __restrict__ bias,
    const float* __restrict__ resid, float* __restrict__ Cout)
{
    __shared__ float As[16][64];   // [k][m]
    __shared__ float Bs[16][64];   // [k][n]
    const int t  = threadIdx.x;
    const int m0 = blockIdx.x * 64;
    const int n0 = blockIdx.y * 64;
    // staging coords
    const int lrow = t >> 2;            // 0..63  A row
    const int lkg  = (t & 3) << 2;      // 0,4,8,12
    const int lkr  = t >> 4;            // 0..15  B k-row
    const int lnc  = (t & 15) << 2;     // 0..60
    // compute coords (16x16 threads of 4x4)
    const int tm = (t & 15) << 2;
    const int tn = (t >> 4) << 2;

    float beta = 1.0f;
    if (FUSE_Z) beta = betap[0];

    float acc[4][4];
    #pragma unroll
    for (int i = 0; i < 4; ++i)
        #pragma unroll
        for (int j = 0; j < 4; ++j) acc[i][j] = 0.f;

    for (int k0 = 0; k0 < C_DIM; k0 += 16) {
        float4 a4 = *(const float4*)&A[(size_t)(m0 + lrow) * C_DIM + k0 + lkg];
        if (FUSE_Z) {
            float4 a2 = *(const float4*)&A2[(size_t)(m0 + lrow) * C_DIM + k0 + lkg];
            a4.x = fmaf(a4.x, beta, a2.x);
            a4.y = fmaf(a4.y, beta, a2.y);
            a4.z = fmaf(a4.z, beta, a2.z);
            a4.w = fmaf(a4.w, beta, a2.w);
        }
        float4 b4 = *(const float4*)&B[(size_t)(k0 + lkr) * C_DIM + n0 + lnc];
        As[lkg + 0][lrow] = a4.x;
        As[lkg + 1][lrow] = a4.y;
        As[lkg + 2][lrow] = a4.z;
        As[lkg + 3][lrow] = a4.w;
        *(float4*)&Bs[lkr][lnc] = b4;
        __syncthreads();
        #pragma unroll
        for (int kk = 0; kk < 16; ++kk) {
            float4 av = *(const float4*)&As[kk][tm];
            float4 bv = *(const float4*)&Bs[kk][tn];
            acc[0][0] = fmaf(av.x, bv.x, acc[0][0]);
            acc[0][1] = fmaf(av.x, bv.y, acc[0][1]);
            acc[0][2] = fmaf(av.x, bv.z, acc[0][2]);
            acc[0][3] = fmaf(av.x, bv.w, acc[0][3]);
            acc[1][0] = fmaf(av.y, bv.x, acc[1][0]);
            acc[1][1] = fmaf(av.y, bv.y, acc[1][1]);
            acc[1][2] = fmaf(av.y, bv.z, acc[1][2]);
            acc[1][3] = fmaf(av.y, bv.w, acc[1][3]);
            acc[2][0] = fmaf(av.z, bv.x, acc[2][0]);
            acc[2][1] = fmaf(av.z, bv.y, acc[2][1]);
            acc[2][2] = fmaf(av.z, bv.z, acc[2][2]);
            acc[2][3] = fmaf(av.z, bv.w, acc[2][3]);
            acc[3][0] = fmaf(av.w, bv.x, acc[3][0]);
            acc[3][1] = fmaf(av.w, bv.y, acc[3][1]);
            acc[3][2] = fmaf(av.w, bv.z, acc[3][2]);
            acc[3][3] = fmaf(av.w, bv.w, acc[3][3]);
        }
        __syncthreads();
    }

    float4 biasv = *(const float4*)&bias[n0 + tn];
    const float bb[4] = {biasv.x, biasv.y, biasv.z, biasv.w};
    #pragma unroll
    for (int i = 0; i < 4; ++i) {
        const size_t row = (size_t)(m0 + tm + i);
        #pragma unroll
        for (int j = 0; j < 4; ++j) {
            float v = acc[i][j] + bb[j];
            if (RELU) v = fmaxf(v, 0.f);
            if (RESID) v += resid[row * C_DIM + n0 + tn + j];
            Cout[row * C_DIM + n0 + tn + j] = v;
        }
    }
}

// ---------------- per-edge: common-neighbor gather + xi*xj ----------------
__global__ __launch_bounds__(256) void k_edges(
    const unsigned long long* __restrict__ bits, const float* __restrict__ x,
    const float* __restrict__ H, const int* __restrict__ tar,
    float* __restrict__ xcn, float* __restrict__ xij)
{
    __shared__ int s_cnt;
    __shared__ int s_idx[256];     // max common neighbors << 256 (max degree ~65)
    const int e = blockIdx.x;
    const int i = tar[e];
    const int j = tar[E_EDGES + e];
    const int t = threadIdx.x;
    if (t == 0) s_cnt = 0;
    __syncthreads();
    const int W = N_NODES / 64;    // 128 words per row
    if (t < W) {
        unsigned long long m = bits[(size_t)i * W + t] & bits[(size_t)j * W + t];
        while (m) {
            int b = __builtin_ctzll(m);
            int slot = atomicAdd(&s_cnt, 1);
            if (slot < 256) s_idx[slot] = (t << 6) + b;
            m &= m - 1;
        }
    }
    __syncthreads();
    const int cnt = min(s_cnt, 256);
    float acc = 0.f;
    for (int q = 0; q < cnt; ++q)
        acc += H[(size_t)s_idx[q] * C_DIM + t];
    xcn[(size_t)e * C_DIM + t] = acc;
    xij[(size_t)e * C_DIM + t] = x[(size_t)i * C_DIM + t] * x[(size_t)j * C_DIM + t];
}

// ---------------- final GEMV: out[e] = L1[e,:] @ w2 + b2 ----------------
__global__ __launch_bounds__(256) void k_gemv_out(const float* __restrict__ L1,
                                                  const float* __restrict__ w2,
                                                  const float* __restrict__ b2,
                                                  float* __restrict__ out) {
    const int gw   = (int)((blockIdx.x * blockDim.x + threadIdx.x) >> 6);
    const int lane = threadIdx.x & 63;
    if (gw >= E_EDGES) return;
    const float* row = L1 + (size_t)gw * C_DIM;
    float s = 0.f;
    #pragma unroll
    for (int c = 0; c < C_DIM; c += 64) s += row[c + lane] * w2[c + lane];
    #pragma unroll
    for (int off = 32; off; off >>= 1) s += __shfl_down(s, off);
    if (lane == 0) out[gw] = s + b2[0];
}

extern "C" void kernel_launch(void* const* d_in, const int* in_sizes, int n_in,
                              void* d_out, int out_size, void* d_ws, size_t ws_size,
                              hipStream_t stream) {
    const float* x       = (const float*)d_in[0];
    const float* adj     = (const float*)d_in[1];
    const int*   tar_ei  = (const int*)  d_in[2];
    const float* xlin_w1 = (const float*)d_in[3];
    const float* xlin_b1 = (const float*)d_in[4];
    const float* xlin_w2 = (const float*)d_in[5];
    const float* xlin_b2 = (const float*)d_in[6];
    const float* xcn_w1  = (const float*)d_in[7];
    const float* xcn_b1  = (const float*)d_in[8];
    const float* xcn_w2  = (const float*)d_in[9];
    const float* xcn_b2  = (const float*)d_in[10];
    const float* xij_w   = (const float*)d_in[11];
    const float* xij_b   = (const float*)d_in[12];
    const float* lin_w1  = (const float*)d_in[13];
    const float* lin_b1  = (const float*)d_in[14];
    const float* lin_w2  = (const float*)d_in[15];
    const float* lin_b2  = (const float*)d_in[16];
    const float* beta    = (const float*)d_in[17];
    float* out = (float*)d_out;

    char* ws = (char*)d_ws;
    const size_t SZ = (size_t)N_NODES * C_DIM * sizeof(float);   // 8 MB
    unsigned long long* bits = (unsigned long long*)(ws);        // 8 MB (8192*128*8)
    float* B1 = (float*)(ws + 1 * SZ);   // tmp
    float* B2 = (float*)(ws + 2 * SZ);   // H
    float* B3 = (float*)(ws + 3 * SZ);   // xcn_raw -> XCN2
    float* B4 = (float*)(ws + 4 * SZ);   // xij_in
    float* B5 = (float*)(ws + 5 * SZ);   // XIJ

    const dim3 gG(N_NODES / 64, C_DIM / 64);   // (128, 4)
    const dim3 b256(256);

    hipLaunchKernelGGL(k_bitmask, dim3(2048), b256, 0, stream, adj, bits);
    hipLaunchKernelGGL((k_gemm256<false, false, true>), gG, b256, 0, stream,
                       x,  nullptr, nullptr, xlin_w1, xlin_b1, nullptr, B1);
    hipLaunchKernelGGL((k_gemm256<false, true,  true>), gG, b256, 0, stream,
                       B1, nullptr, nullptr, xlin_w2, xlin_b2, x,      B2);
    hipLaunchKernelGGL(k_edges, dim3(E_EDGES), b256, 0, stream,
                       bits, x, B2, tar_ei, B3, B4);
    hipLaunchKernelGGL((k_gemm256<false, false, true>), gG, b256, 0, stream,
                       B4, nullptr, nullptr, xij_w,  xij_b,  nullptr, B5);
    hipLaunchKernelGGL((k_gemm256<false, false, true>), gG, b256, 0, stream,
                       B3, nullptr, nullptr, xcn_w1, xcn_b1, nullptr, B1);
    hipLaunchKernelGGL((k_gemm256<false, false, true>), gG, b256, 0, stream,
                       B1, nullptr, nullptr, xcn_w2, xcn_b2, nullptr, B3);
    hipLaunchKernelGGL((k_gemm256<true,  false, true>), gG, b256, 0, stream,
                       B3, B5, beta, lin_w1, lin_b1, nullptr, B1);
    hipLaunchKernelGGL(k_gemv_out, dim3(E_EDGES / 4), b256, 0, stream,
                       B1, lin_w2, lin_b2, out);
}